// Round 3
// baseline (353.172 us; speedup 1.0000x reference)
//
#include <hip/hip_runtime.h>
#include <hip/hip_bf16.h>

#define NN 50000
#define EE 800000
#define SCAN_B 2048
#define NB ((NN + SCAN_B - 1) / SCAN_B)   // 25 scan blocks

// NOTE: harness materializes integer inputs as int32 -> edge_index is const int*.
// NOTE (r7): fp32 scatter atomics = ~80us atomic-latency wall. Avoided.
// NOTE (r9): CSR holds real edges only; self-loop handled inline in agg kernels.
// NOTE (r10/r11): three different agg1 schedules all pin at 77us / ~3.7 TB/s
//             beyond-L2 -> traffic wall, not scheduling. Bank conflicts ~free.
// NOTE (r12): layer1 restructured: aggregate x (256B rows) not h1 (512B rows),
//             then project per node. Gather bytes halved (410->205MB), layer-1
//             GEMM over h1 removed; asrc/adst via factored x @ (W1 a) (Asd).
//             g2_bf aliases Sx (dead after proj1) to bound workspace growth.

typedef short bf16x8 __attribute__((ext_vector_type(8)));
typedef float f32x4  __attribute__((ext_vector_type(4)));

__device__ __forceinline__ float bf2f(unsigned short u) {
    return __uint_as_float(((unsigned)u) << 16);
}
__device__ __forceinline__ unsigned short f2bf(float f) {
    unsigned b = __float_as_uint(f);
    b += 0x7fffu + ((b >> 16) & 1u);           // RNE
    return (unsigned short)(b >> 16);
}
// dword holding two bf16 -> two floats (1 shl + 1 and)
__device__ __forceinline__ float2 bfpair(unsigned u) {
    return make_float2(__uint_as_float(u << 16), __uint_as_float(u & 0xffff0000u));
}

// ---------------- fused prep: v-proj + Asd + Wt casts + hist/rank + x cast ----
// block 0: v + Asd ; blocks [1,256]: Wt ; [257,3381]: hist+rank ; rest: castx
__global__ void k_prep(const float* __restrict__ We1, const float* __restrict__ ae1,
                       const float* __restrict__ We2, const float* __restrict__ ae2,
                       float* __restrict__ v,
                       const float* __restrict__ as1, const float* __restrict__ ad1,
                       float* __restrict__ Asd,
                       const float* __restrict__ W1, unsigned short* __restrict__ W1t,
                       const float* __restrict__ W2, unsigned short* __restrict__ W2t,
                       const int* __restrict__ ei, int* __restrict__ idg,
                       int* __restrict__ rank,
                       const float* __restrict__ x, unsigned short* __restrict__ xb) {
    int bid = blockIdx.x, t = threadIdx.x;
    if (bid == 0) {
        if (t < 8) {            // layer1: c=t>>2, h=t&3 -> v[c*4+h]
            int c = t >> 2, h = t & 3;
            float s = 0.f;
            for (int d = 0; d < 64; d++) s += We1[c * 256 + h * 64 + d] * ae1[h * 64 + d];
            v[c * 4 + h] = s;
        } else if (t < 10) {    // layer2: c=t-8 -> v[8+c]
            int c = t - 8;
            float s = 0.f;
            for (int d = 0; d < 128; d++) s += We2[c * 128 + d] * ae2[d];
            v[8 + c] = s;
        }
        // Asd[k*8+j]: j<4 -> sum_c W1[k,j*64+c]*as1[j,c]; j>=4 -> same with ad1
        #pragma unroll 1
        for (int idx = t; idx < 1024; idx += 256) {
            int k = idx >> 3, j = idx & 7;
            const float* a = (j < 4) ? as1 : ad1;
            int h = j & 3;
            float s = 0.f;
            for (int c = 0; c < 64; c++) s += W1[k * 256 + h * 64 + c] * a[h * 64 + c];
            Asd[idx] = s;
        }
    } else if (bid <= 256) {
        int idx = (bid - 1) * 256 + t;
        if (idx < 32768) {                 // W1: 128x256 -> 256x128
            int k = idx >> 8, n = idx & 255;
            W1t[n * 128 + k] = f2bf(W1[idx]);
        } else {                           // W2: 256x128 -> 128x256
            int i = idx - 32768;
            int k = i >> 7, n = i & 127;
            W2t[n * 256 + k] = f2bf(W2[i]);
        }
    } else if (bid <= 256 + 3125) {
        int e = (bid - 257) * 256 + t;
        if (e < EE) rank[e] = atomicAdd(&idg[ei[EE + e]], 1);
    } else {
        int i = (bid - 3382) * 256 + t;
        if (i < NN * 128 / 4) {
            float4 vv = ((const float4*)x)[i];
            ushort4 o;
            o.x = f2bf(vv.x); o.y = f2bf(vv.y); o.z = f2bf(vv.z); o.w = f2bf(vv.w);
            ((ushort4*)xb)[i] = o;
        }
    }
}

// ---------------- CSR build: 3-pass exclusive scan of idg -> rowptr -----------
__global__ void k_scan1(const int* __restrict__ idg, int* __restrict__ rowptr,
                        int* __restrict__ bsum) {
    __shared__ int sh[512];
    int t = threadIdx.x;
    int base = blockIdx.x * SCAN_B + t * 4;
    int v[4]; int s = 0;
    #pragma unroll
    for (int j = 0; j < 4; j++) {
        int i = base + j;
        v[j] = (i < NN) ? idg[i] : 0;
        s += v[j];
    }
    sh[t] = s;
    __syncthreads();
    for (int off = 1; off < 512; off <<= 1) {
        int a = (t >= off) ? sh[t - off] : 0;
        __syncthreads();
        sh[t] += a;
        __syncthreads();
    }
    int run = sh[t] - s;
    #pragma unroll
    for (int j = 0; j < 4; j++) {
        int i = base + j;
        if (i < NN) rowptr[i] = run;
        run += v[j];
    }
    if (t == 511) bsum[blockIdx.x] = sh[511];
}

__global__ void k_scan2(const int* __restrict__ bsum, int* __restrict__ boff,
                        int* __restrict__ rowptr) {
    if (threadIdx.x == 0) {
        int acc = 0;
        for (int b = 0; b < NB; b++) { boff[b] = acc; acc += bsum[b]; }
        rowptr[NN] = acc;      // == EE
    }
}

__global__ void k_scan3(int* __restrict__ rowptr, const int* __restrict__ boff) {
    int t = threadIdx.x;
    int i = blockIdx.x * SCAN_B + t * 4;
    int off = boff[blockIdx.x];
    #pragma unroll
    for (int j = 0; j < 4; j++)
        if (i + j < NN) rowptr[i + j] += off;
}

// ---------------- atomic-free scatter: p = rowptr[dst] + rank[e] --------------
__global__ void k_scatter(const int* __restrict__ ei, const float* __restrict__ eattr,
                          const int* __restrict__ rowptr, const int* __restrict__ rank,
                          int2* __restrict__ slot) {
    int e = blockIdx.x * blockDim.x + threadIdx.x;
    if (e >= EE) return;
    int s = ei[e], d = ei[EE + e];
    int p = rowptr[d] + rank[e];
    float2 a = ((const float2*)eattr)[e];
    unsigned a0 = f2bf(a.x), a1 = f2bf(a.y);
    slot[p] = make_int2(s, (int)(a0 | (a1 << 16)));
}

// ---------------- layer1 attn scalars: asrc/adst = x . Asd (factored) ---------
// one wave / node; lane owns 2 channels (one dword of x_bf).
__global__ __launch_bounds__(256) void k_attn1(const unsigned short* __restrict__ xb,
                       const float* __restrict__ Asd,
                       float* __restrict__ asrc, float* __restrict__ adst) {
    int node = blockIdx.x * 4 + (threadIdx.x >> 6);
    if (node >= NN) return;
    int lane = threadIdx.x & 63;
    unsigned xw = *(const unsigned*)(xb + (size_t)node * 128 + lane * 2);
    float2 xc = bfpair(xw);
    const float4* A4 = (const float4*)Asd;     // [k][8] -> float4 pairs
    float4 s0 = A4[lane * 4 + 0];              // k=2l  src
    float4 d0 = A4[lane * 4 + 1];              // k=2l  dst
    float4 s1 = A4[lane * 4 + 2];              // k=2l+1 src
    float4 d1 = A4[lane * 4 + 3];              // k=2l+1 dst
    float r[8];
    r[0] = xc.x * s0.x + xc.y * s1.x;
    r[1] = xc.x * s0.y + xc.y * s1.y;
    r[2] = xc.x * s0.z + xc.y * s1.z;
    r[3] = xc.x * s0.w + xc.y * s1.w;
    r[4] = xc.x * d0.x + xc.y * d1.x;
    r[5] = xc.x * d0.y + xc.y * d1.y;
    r[6] = xc.x * d0.z + xc.y * d1.z;
    r[7] = xc.x * d0.w + xc.y * d1.w;
    #pragma unroll
    for (int off = 1; off < 64; off <<= 1)
        #pragma unroll
        for (int j = 0; j < 8; j++) r[j] += __shfl_xor(r[j], off);
    if (lane == 0) {
        *(float4*)(asrc + node * 4) = make_float4(r[0], r[1], r[2], r[3]);
        *(float4*)(adst + node * 4) = make_float4(r[4], r[5], r[6], r[7]);
    }
}

// ---------------- layer1 softmax+aggregate of X (pre-projection) --------------
// one wave / node; quarter-wave (16 lanes x 16B) per edge, 4 edges / iter.
// Lane ql owns x channels [ql*8, ql*8+8) and accumulates all 4 heads (32 acc).
// All-head alphas from one contiguous float4 asrc load. Rotating clamped slot
// prefetch; no main-loop shuffles. Sx[n][h][k] = (sum coef_h x[src] + self)/den.
__global__ __launch_bounds__(256) void k_agg1x(const int* __restrict__ rowptr,
                       const int2* __restrict__ slot, const float* __restrict__ asrc,
                       const float* __restrict__ adst, const float* __restrict__ v,
                       const unsigned short* __restrict__ xb,
                       unsigned short* __restrict__ Sx) {
    int node = blockIdx.x * 4 + (threadIdx.x >> 6);
    if (node >= NN) return;
    int lane = threadIdx.x & 63;
    int q  = lane >> 4;          // edge-in-group
    int ql = lane & 15;          // channel-lane: owns ch [ql*8, ql*8+8)
    int beg = rowptr[node], end = rowptr[node + 1];
    float4 pd4 = *(const float4*)(adst + node * 4);
    float pd[4] = {pd4.x, pd4.y, pd4.z, pd4.w};
    float v0[4] = {v[0], v[1], v[2], v[3]};
    float v1[4] = {v[4], v[5], v[6], v[7]};
    float acc[4][8] = {};
    float den[4] = {};
    float s0 = 0.f, s1 = 0.f;
    const unsigned short* xbq = xb + ql * 8;

    int cnt = end - beg;
    int safeLast = max(end - 1, 0);
    int mend = beg + (cnt & ~3);

    int2 sl0 = slot[min(beg + q, safeLast)];
    int2 sl1 = slot[min(beg + 4 + q, safeLast)];

    auto body = [&](int2 cur) {
        int s = cur.x;
        float2 a = bfpair((unsigned)cur.y);
        float4 as4 = *(const float4*)(asrc + s * 4);
        float as_[4] = {as4.x, as4.y, as4.z, as4.w};
        uint4 r = *(const uint4*)(xbq + (size_t)s * 128);
        float e[4];
        #pragma unroll
        for (int h = 0; h < 4; h++) {
            float al = as_[h] + pd[h] + a.x * v0[h] + a.y * v1[h];
            al = (al > 0.f) ? al : 0.2f * al;
            e[h] = __expf(al);
            den[h] += e[h];
        }
        s0 += a.x; s1 += a.y;
        float xx[8];
        float2 p;
        p = bfpair(r.x); xx[0] = p.x; xx[1] = p.y;
        p = bfpair(r.y); xx[2] = p.x; xx[3] = p.y;
        p = bfpair(r.z); xx[4] = p.x; xx[5] = p.y;
        p = bfpair(r.w); xx[6] = p.x; xx[7] = p.y;
        #pragma unroll
        for (int h = 0; h < 4; h++)
            #pragma unroll
            for (int c = 0; c < 8; c++) acc[h][c] += e[h] * xx[c];
    };

    #pragma unroll 2
    for (int pb = beg; pb < mend; pb += 4) {
        int2 cur = sl0;
        sl0 = sl1;
        sl1 = slot[min(pb + 8 + q, safeLast)];
        body(cur);
    }
    if (mend + q < end) body(sl0);          // tail edges

    // cross-quarter reductions
    #pragma unroll
    for (int h = 0; h < 4; h++)
        #pragma unroll
        for (int c = 0; c < 8; c++) {
            acc[h][c] += __shfl_down(acc[h][c], 32);
            acc[h][c] += __shfl_down(acc[h][c], 16);
        }
    #pragma unroll
    for (int h = 0; h < 4; h++) {
        den[h] += __shfl_xor(den[h], 16);
        den[h] += __shfl_xor(den[h], 32);
    }
    s0 += __shfl_xor(s0, 16); s0 += __shfl_xor(s0, 32);
    s1 += __shfl_xor(s1, 16); s1 += __shfl_xor(s1, 32);

    // self-loop: mean attrs over real edges (0 if none)
    float dg = fmaxf((float)cnt, 1.0f);
    float4 an4 = *(const float4*)(asrc + node * 4);
    float an[4] = {an4.x, an4.y, an4.z, an4.w};
    float exs[4];
    #pragma unroll
    for (int h = 0; h < 4; h++) {
        float als = an[h] + pd[h] + (s0 / dg) * v0[h] + (s1 / dg) * v1[h];
        als = (als > 0.f) ? als : 0.2f * als;
        exs[h] = __expf(als);
        den[h] += exs[h];
    }

    if (q == 0) {
        uint4 r = *(const uint4*)(xbq + (size_t)node * 128);
        float xx[8];
        float2 p;
        p = bfpair(r.x); xx[0] = p.x; xx[1] = p.y;
        p = bfpair(r.y); xx[2] = p.x; xx[3] = p.y;
        p = bfpair(r.z); xx[4] = p.x; xx[5] = p.y;
        p = bfpair(r.w); xx[6] = p.x; xx[7] = p.y;
        #pragma unroll
        for (int h = 0; h < 4; h++) {
            float inv = 1.f / (den[h] + 1e-16f);
            short ov[8];
            #pragma unroll
            for (int c = 0; c < 8; c++)
                ov[c] = (short)f2bf((acc[h][c] + exs[h] * xx[c]) * inv);
            bf16x8 o8 = {ov[0], ov[1], ov[2], ov[3], ov[4], ov[5], ov[6], ov[7]};
            *(bf16x8*)(Sx + (size_t)node * 512 + h * 128 + ql * 8) = o8;
        }
    }
}

// ---------------- layer1 projection: h2 = ELU(Sx @ W1 (per head) + b1) --------
// grid (4 heads, node/128); per block: 128 rows x 64 cols of head h.
__global__ __launch_bounds__(256) void k_proj1(const unsigned short* __restrict__ Sx,
                       const unsigned short* __restrict__ W1t,
                       const float* __restrict__ b1,
                       unsigned short* __restrict__ h2b) {
    int h = blockIdx.x;
    int wave = threadIdx.x >> 6, lane = threadIdx.x & 63;
    int l16 = lane & 15, quad = lane >> 4;
    int m0 = blockIdx.y * 128 + wave * 32;

    f32x4 acc[2][4];
    #pragma unroll
    for (int mt = 0; mt < 2; mt++)
        #pragma unroll
        for (int nt = 0; nt < 4; nt++)
            acc[mt][nt] = (f32x4){0.f, 0.f, 0.f, 0.f};

    int ar0 = min(m0 + l16, NN - 1);
    int ar1 = min(m0 + 16 + l16, NN - 1);
    const unsigned short* a0 = Sx + (size_t)ar0 * 512 + h * 128 + quad * 8;
    const unsigned short* a1 = Sx + (size_t)ar1 * 512 + h * 128 + quad * 8;
    const unsigned short* bp = W1t + (size_t)(h * 64 + l16) * 128 + quad * 8;

    #pragma unroll
    for (int k0 = 0; k0 < 128; k0 += 32) {
        bf16x8 af0 = *(const bf16x8*)(a0 + k0);
        bf16x8 af1 = *(const bf16x8*)(a1 + k0);
        #pragma unroll
        for (int nt = 0; nt < 4; nt++) {
            bf16x8 bf = *(const bf16x8*)(bp + (size_t)nt * 16 * 128 + k0);
            acc[0][nt] = __builtin_amdgcn_mfma_f32_16x16x32_bf16(af0, bf, acc[0][nt], 0, 0, 0);
            acc[1][nt] = __builtin_amdgcn_mfma_f32_16x16x32_bf16(af1, bf, acc[1][nt], 0, 0, 0);
        }
    }

    float bia[4];
    #pragma unroll
    for (int nt = 0; nt < 4; nt++) bia[nt] = b1[h * 64 + nt * 16 + l16];

    // C layout: col = l16, row = quad*4 + reg
    #pragma unroll
    for (int mt = 0; mt < 2; mt++)
        #pragma unroll
        for (int reg = 0; reg < 4; reg++) {
            int row = m0 + mt * 16 + quad * 4 + reg;
            if (row < NN) {
                #pragma unroll
                for (int nt = 0; nt < 4; nt++) {
                    float va = acc[mt][nt][reg] + bia[nt];
                    va = (va > 0.f) ? va : __expf(va) - 1.f;   // ELU
                    h2b[(size_t)row * 256 + h * 64 + nt * 16 + l16] = f2bf(va);
                }
            }
        }
}

// ---------------- MFMA bf16 GEMM with fused attention-scalar epilogue ---------
// (layer 2 only now) C[M,N] = A[M,K] @ Bt[N,K]^T (bf16 out).
template <int K, int NT, int H>
__global__ __launch_bounds__(256) void gemm_mfma(const unsigned short* __restrict__ A,
                                                 const unsigned short* __restrict__ Bt,
                                                 unsigned short* __restrict__ C,
                                                 const float* __restrict__ avs,
                                                 const float* __restrict__ avd,
                                                 float* __restrict__ asrc,
                                                 float* __restrict__ adst,
                                                 int M, int N) {
    int wave = threadIdx.x >> 6, lane = threadIdx.x & 63;
    int l16 = lane & 15, quad = lane >> 4;
    int m0 = blockIdx.y * 128 + wave * 32;
    int n0 = blockIdx.x * (NT * 16);

    f32x4 acc[2][NT];
    #pragma unroll
    for (int mt = 0; mt < 2; mt++)
        #pragma unroll
        for (int nt = 0; nt < NT; nt++)
            acc[mt][nt] = (f32x4){0.f, 0.f, 0.f, 0.f};

    int ar0 = min(m0 + l16, M - 1);
    int ar1 = min(m0 + 16 + l16, M - 1);
    const unsigned short* a0 = A + (size_t)ar0 * K + quad * 8;
    const unsigned short* a1 = A + (size_t)ar1 * K + quad * 8;
    const unsigned short* bp = Bt + (size_t)(n0 + l16) * K + quad * 8;

    #pragma unroll
    for (int k0 = 0; k0 < K; k0 += 32) {
        bf16x8 af0 = *(const bf16x8*)(a0 + k0);
        bf16x8 af1 = *(const bf16x8*)(a1 + k0);
        #pragma unroll
        for (int nt = 0; nt < NT; nt++) {
            bf16x8 bf = *(const bf16x8*)(bp + (size_t)nt * 16 * K + k0);
            acc[0][nt] = __builtin_amdgcn_mfma_f32_16x16x32_bf16(af0, bf, acc[0][nt], 0, 0, 0);
            acc[1][nt] = __builtin_amdgcn_mfma_f32_16x16x32_bf16(af1, bf, acc[1][nt], 0, 0, 0);
        }
    }

    // C store. C/D layout: col = l16, row = quad*4 + reg
    #pragma unroll
    for (int mt = 0; mt < 2; mt++)
        #pragma unroll
        for (int reg = 0; reg < 4; reg++) {
            int row = m0 + mt * 16 + quad * 4 + reg;
            if (row < M) {
                #pragma unroll
                for (int nt = 0; nt < NT; nt++)
                    C[(size_t)row * N + n0 + nt * 16 + l16] = f2bf(acc[mt][nt][reg]);
            }
        }

    // fused attn scalars: asrc/adst[row, head] from fp32 acc
    float ws[NT], wd[NT];
    #pragma unroll
    for (int nt = 0; nt < NT; nt++) {
        ws[nt] = avs[n0 + nt * 16 + l16];
        wd[nt] = avd[n0 + nt * 16 + l16];
    }
    int hh = n0 >> 6;          // head index (layer2: 0)
    #pragma unroll
    for (int mt = 0; mt < 2; mt++)
        #pragma unroll
        for (int reg = 0; reg < 4; reg++) {
            int row = m0 + mt * 16 + quad * 4 + reg;
            float s1 = 0.f, s2 = 0.f;
            #pragma unroll
            for (int nt = 0; nt < NT; nt++) {
                float c = acc[mt][nt][reg];
                s1 += c * ws[nt];
                s2 += c * wd[nt];
            }
            #pragma unroll
            for (int off = 1; off < 16; off <<= 1) {
                s1 += __shfl_xor(s1, off);
                s2 += __shfl_xor(s2, off);
            }
            if (l16 == 0 && row < M) {
                asrc[row * H + hh] = s1;
                adst[row * H + hh] = s2;
            }
        }
}

// ---------------- layer2 fused softmax+aggregate+bias (H=1, 128ch, fp32 out) --
// quarter-wave per edge (full 256B row per 16 lanes); rotating clamped prefetch.
__global__ __launch_bounds__(256) void k_agg2(const int* __restrict__ rowptr,
                       const int2* __restrict__ slot, const float* __restrict__ asrc,
                       const float* __restrict__ adst, const float* __restrict__ v,
                       const unsigned short* __restrict__ gb, const float* __restrict__ b2,
                       float* __restrict__ outp) {
    int node = blockIdx.x * 4 + (threadIdx.x >> 6);
    if (node >= NN) return;
    int lane = threadIdx.x & 63;
    int q  = lane >> 4;          // edge-in-group
    int ql = lane & 15;          // channel-lane (8 ch each)
    int beg = rowptr[node], end = rowptr[node + 1];
    float ad = adst[node];
    float v0 = v[0], v1 = v[1];
    float acc[8] = {};
    float den = 0.f, s0 = 0.f, s1 = 0.f;
    const unsigned short* gbq = gb + ql * 8;

    int cnt = end - beg;
    int safeLast = max(end - 1, 0);
    int mend = beg + (cnt & ~3);

    int2 sl0 = slot[min(beg + q, safeLast)];
    int2 sl1 = slot[min(beg + 4 + q, safeLast)];

    auto body = [&](int2 cur) {
        int s = cur.x;
        float2 a = bfpair((unsigned)cur.y);
        float al = asrc[s] + ad + a.x * v0 + a.y * v1;
        al = (al > 0.f) ? al : 0.2f * al;
        float e = __expf(al);
        s0 += a.x; s1 += a.y; den += e;
        uint4 r = *(const uint4*)(gbq + (size_t)s * 128);
        float2 p;
        p = bfpair(r.x); acc[0] += e * p.x; acc[1] += e * p.y;
        p = bfpair(r.y); acc[2] += e * p.x; acc[3] += e * p.y;
        p = bfpair(r.z); acc[4] += e * p.x; acc[5] += e * p.y;
        p = bfpair(r.w); acc[6] += e * p.x; acc[7] += e * p.y;
    };

    #pragma unroll 2
    for (int pb = beg; pb < mend; pb += 4) {
        int2 cur = sl0;
        sl0 = sl1;
        sl1 = slot[min(pb + 8 + q, safeLast)];
        body(cur);
    }
    if (mend + q < end) body(sl0);          // tail edges

    #pragma unroll
    for (int k = 0; k < 8; k++) {
        acc[k] += __shfl_down(acc[k], 32);
        acc[k] += __shfl_down(acc[k], 16);
    }
    den += __shfl_xor(den, 16); den += __shfl_xor(den, 32);
    s0  += __shfl_xor(s0, 16);  s0  += __shfl_xor(s0, 32);
    s1  += __shfl_xor(s1, 16);  s1  += __shfl_xor(s1, 32);

    // self-loop epilogue
    float dg = fmaxf((float)cnt, 1.0f);
    float als = asrc[node] + ad + (s0 / dg) * v0 + (s1 / dg) * v1;
    als = (als > 0.f) ? als : 0.2f * als;
    float exs = __expf(als);
    den += exs;

    if (q == 0) {
        uint4 r = *(const uint4*)(gbq + (size_t)node * 128);
        float2 p;
        p = bfpair(r.x); acc[0] += exs * p.x; acc[1] += exs * p.y;
        p = bfpair(r.y); acc[2] += exs * p.x; acc[3] += exs * p.y;
        p = bfpair(r.z); acc[4] += exs * p.x; acc[5] += exs * p.y;
        p = bfpair(r.w); acc[6] += exs * p.x; acc[7] += exs * p.y;
        float inv = 1.f / (den + 1e-16f);
        float4 o0, o1;
        o0.x = acc[0] * inv + b2[ql * 8 + 0];
        o0.y = acc[1] * inv + b2[ql * 8 + 1];
        o0.z = acc[2] * inv + b2[ql * 8 + 2];
        o0.w = acc[3] * inv + b2[ql * 8 + 3];
        o1.x = acc[4] * inv + b2[ql * 8 + 4];
        o1.y = acc[5] * inv + b2[ql * 8 + 5];
        o1.z = acc[6] * inv + b2[ql * 8 + 6];
        o1.w = acc[7] * inv + b2[ql * 8 + 7];
        *(float4*)(outp + (size_t)node * 128 + ql * 8)     = o0;
        *(float4*)(outp + (size_t)node * 128 + ql * 8 + 4) = o1;
    }
}

extern "C" void kernel_launch(void* const* d_in, const int* in_sizes, int n_in,
                              void* d_out, int out_size, void* d_ws, size_t ws_size,
                              hipStream_t stream) {
    const float* x     = (const float*)d_in[0];
    const int*   ei    = (const int*)d_in[1];      // int32 on device
    const float* eattr = (const float*)d_in[2];
    const float* W1    = (const float*)d_in[3];
    const float* We1   = (const float*)d_in[4];
    const float* as1   = (const float*)d_in[5];
    const float* ad1   = (const float*)d_in[6];
    const float* ae1   = (const float*)d_in[7];
    const float* b1    = (const float*)d_in[8];
    const float* W2    = (const float*)d_in[9];
    const float* We2   = (const float*)d_in[10];
    const float* as2   = (const float*)d_in[11];
    const float* ad2   = (const float*)d_in[12];
    const float* ae2   = (const float*)d_in[13];
    const float* b2    = (const float*)d_in[14];
    float* out = (float*)d_out;

    // ---- workspace carve ----
    int* idg    = (int*)d_ws;                      // NN
    int* rank   = idg + NN;                        // EE
    int* rowptr = rank + EE;                       // NN+16
    int* bsum   = rowptr + NN + 16;                // 32
    int* boff   = bsum + 32;                       // 32
    int2* slot  = (int2*)(boff + 32);              // EE (8B-aligned)
    float* asrc1 = (float*)(slot + EE);            // 4*NN
    float* adst1 = asrc1 + 4 * NN;                 // 4*NN
    float* asrc2 = adst1 + 4 * NN;                 // NN
    float* adst2 = asrc2 + NN;                     // NN
    float* vbuf  = adst2 + NN;                     // 64
    float* Asd   = vbuf + 64;                      // 1024
    unsigned short* ub = (unsigned short*)(((uintptr_t)(Asd + 1024) + 63) & ~(uintptr_t)63);
    unsigned short* x_bf  = ub;                      // NN*128
    unsigned short* W1t   = x_bf + (size_t)NN * 128; // 256*128
    unsigned short* W2t   = W1t + 32768;             // 128*256
    unsigned short* Sx    = W2t + 32768;             // NN*512
    unsigned short* h2_bf = Sx + (size_t)NN * 512;   // NN*256
    unsigned short* g2_bf = Sx;                      // alias: Sx dead after proj1

    hipMemsetAsync(idg, 0, (size_t)NN * sizeof(int), stream);

    // prep (v, Asd, Wt casts, degree hist + rank, x cast) + CSR build
    k_prep<<<9632, 256, 0, stream>>>(We1, ae1, We2, ae2, vbuf, as1, ad1, Asd,
                                     W1, W1t, W2, W2t, ei, idg, rank, x, x_bf);
    k_scan1<<<NB, 512, 0, stream>>>(idg, rowptr, bsum);
    k_scan2<<<1, 64, 0, stream>>>(bsum, boff, rowptr);
    k_scan3<<<NB, 512, 0, stream>>>(rowptr, boff);
    k_scatter<<<(EE + 255) / 256, 256, 0, stream>>>(ei, eattr, rowptr, rank, slot);

    // ---- layer 1 ----  (attn scalars, aggregate x, project)
    k_attn1<<<(NN + 3) / 4, 256, 0, stream>>>(x_bf, Asd, asrc1, adst1);
    k_agg1x<<<(NN + 3) / 4, 256, 0, stream>>>(rowptr, slot, asrc1, adst1, vbuf,
                                              x_bf, Sx);
    k_proj1<<<dim3(4, (NN + 127) / 128), 256, 0, stream>>>(Sx, W1t, b1, h2_bf);

    // ---- layer 2 ----
    gemm_mfma<256, 8, 1><<<dim3(1, (NN + 127) / 128), 256, 0, stream>>>(
        h2_bf, W2t, g2_bf, as2, ad2, asrc2, adst2, NN, 128);
    k_agg2<<<(NN + 3) / 4, 256, 0, stream>>>(rowptr, slot, asrc2, adst2, vbuf + 8,
                                             g2_bf, b2, out);
}

// Round 4
// 348.571 us; speedup vs baseline: 1.0132x; 1.0132x over previous
//
#include <hip/hip_runtime.h>
#include <hip/hip_bf16.h>

#define NN 50000
#define EE 800000
#define SCAN_B 2048
#define NB ((NN + SCAN_B - 1) / SCAN_B)   // 25 scan blocks
#define LOG2E 1.44269504088896340736f

// NOTE: harness materializes integer inputs as int32 -> edge_index is const int*.
// NOTE (r7): fp32 scatter atomics = ~80us atomic-latency wall. Avoided.
// NOTE (r9): CSR holds real edges only; self-loop handled inline in agg kernels.
// NOTE (r10/r11): agg1-over-h1 pins at 77us / ~3.7 TB/s -> traffic wall.
// NOTE (r12): aggregate x (256B rows) then project: FETCH 253->139MB confirmed,
//             but scalar 4-head body = 22.5 wave-ops/edge -> VALU-bound (76%).
// NOTE (r13): packed f32x2 math (v_pk_fma_f32), exp2-domain alphas (Asd/v/ws/wd
//             pre-scaled by log2e -> 1-instr exp), 3-stream rotating prefetch
//             (slot + asrc + xrow one iter ahead). Same bytes, ~14.5 ops/edge.

typedef short bf16x8 __attribute__((ext_vector_type(8)));
typedef float f32x4  __attribute__((ext_vector_type(4)));
typedef float f32x2  __attribute__((ext_vector_type(2)));

__device__ __forceinline__ float bf2f(unsigned short u) {
    return __uint_as_float(((unsigned)u) << 16);
}
__device__ __forceinline__ unsigned short f2bf(float f) {
    unsigned b = __float_as_uint(f);
    b += 0x7fffu + ((b >> 16) & 1u);           // RNE
    return (unsigned short)(b >> 16);
}
// dword holding two bf16 -> two floats (1 shl + 1 and)
__device__ __forceinline__ float2 bfpair(unsigned u) {
    return make_float2(__uint_as_float(u << 16), __uint_as_float(u & 0xffff0000u));
}
__device__ __forceinline__ f32x2 bfpair2(unsigned u) {
    f32x2 r;
    r.x = __uint_as_float(u << 16);
    r.y = __uint_as_float(u & 0xffff0000u);
    return r;
}

// ---------------- fused prep: v-proj + Asd + Wt casts + hist/rank + x cast ----
// v and Asd are pre-scaled by log2e: alphas live in exp2 domain downstream.
__global__ void k_prep(const float* __restrict__ We1, const float* __restrict__ ae1,
                       const float* __restrict__ We2, const float* __restrict__ ae2,
                       float* __restrict__ v,
                       const float* __restrict__ as1, const float* __restrict__ ad1,
                       float* __restrict__ Asd,
                       const float* __restrict__ W1, unsigned short* __restrict__ W1t,
                       const float* __restrict__ W2, unsigned short* __restrict__ W2t,
                       const int* __restrict__ ei, int* __restrict__ idg,
                       int* __restrict__ rank,
                       const float* __restrict__ x, unsigned short* __restrict__ xb) {
    int bid = blockIdx.x, t = threadIdx.x;
    if (bid == 0) {
        if (t < 8) {            // layer1: c=t>>2, h=t&3 -> v[c*4+h]
            int c = t >> 2, h = t & 3;
            float s = 0.f;
            for (int d = 0; d < 64; d++) s += We1[c * 256 + h * 64 + d] * ae1[h * 64 + d];
            v[c * 4 + h] = s * LOG2E;
        } else if (t < 10) {    // layer2: c=t-8 -> v[8+c]
            int c = t - 8;
            float s = 0.f;
            for (int d = 0; d < 128; d++) s += We2[c * 128 + d] * ae2[d];
            v[8 + c] = s * LOG2E;
        }
        // Asd[k*8+j]: j<4 -> sum_c W1[k,j*64+c]*as1[j,c]; j>=4 -> same with ad1
        #pragma unroll 1
        for (int idx = t; idx < 1024; idx += 256) {
            int k = idx >> 3, j = idx & 7;
            const float* a = (j < 4) ? as1 : ad1;
            int h = j & 3;
            float s = 0.f;
            for (int c = 0; c < 64; c++) s += W1[k * 256 + h * 64 + c] * a[h * 64 + c];
            Asd[idx] = s * LOG2E;
        }
    } else if (bid <= 256) {
        int idx = (bid - 1) * 256 + t;
        if (idx < 32768) {                 // W1: 128x256 -> 256x128
            int k = idx >> 8, n = idx & 255;
            W1t[n * 128 + k] = f2bf(W1[idx]);
        } else {                           // W2: 256x128 -> 128x256
            int i = idx - 32768;
            int k = i >> 7, n = i & 127;
            W2t[n * 256 + k] = f2bf(W2[i]);
        }
    } else if (bid <= 256 + 3125) {
        int e = (bid - 257) * 256 + t;
        if (e < EE) rank[e] = atomicAdd(&idg[ei[EE + e]], 1);
    } else {
        int i = (bid - 3382) * 256 + t;
        if (i < NN * 128 / 4) {
            float4 vv = ((const float4*)x)[i];
            ushort4 o;
            o.x = f2bf(vv.x); o.y = f2bf(vv.y); o.z = f2bf(vv.z); o.w = f2bf(vv.w);
            ((ushort4*)xb)[i] = o;
        }
    }
}

// ---------------- CSR build: 3-pass exclusive scan of idg -> rowptr -----------
__global__ void k_scan1(const int* __restrict__ idg, int* __restrict__ rowptr,
                        int* __restrict__ bsum) {
    __shared__ int sh[512];
    int t = threadIdx.x;
    int base = blockIdx.x * SCAN_B + t * 4;
    int v[4]; int s = 0;
    #pragma unroll
    for (int j = 0; j < 4; j++) {
        int i = base + j;
        v[j] = (i < NN) ? idg[i] : 0;
        s += v[j];
    }
    sh[t] = s;
    __syncthreads();
    for (int off = 1; off < 512; off <<= 1) {
        int a = (t >= off) ? sh[t - off] : 0;
        __syncthreads();
        sh[t] += a;
        __syncthreads();
    }
    int run = sh[t] - s;
    #pragma unroll
    for (int j = 0; j < 4; j++) {
        int i = base + j;
        if (i < NN) rowptr[i] = run;
        run += v[j];
    }
    if (t == 511) bsum[blockIdx.x] = sh[511];
}

__global__ void k_scan2(const int* __restrict__ bsum, int* __restrict__ boff,
                        int* __restrict__ rowptr) {
    if (threadIdx.x == 0) {
        int acc = 0;
        for (int b = 0; b < NB; b++) { boff[b] = acc; acc += bsum[b]; }
        rowptr[NN] = acc;      // == EE
    }
}

__global__ void k_scan3(int* __restrict__ rowptr, const int* __restrict__ boff) {
    int t = threadIdx.x;
    int i = blockIdx.x * SCAN_B + t * 4;
    int off = boff[blockIdx.x];
    #pragma unroll
    for (int j = 0; j < 4; j++)
        if (i + j < NN) rowptr[i + j] += off;
}

// ---------------- atomic-free scatter: p = rowptr[dst] + rank[e] --------------
__global__ void k_scatter(const int* __restrict__ ei, const float* __restrict__ eattr,
                          const int* __restrict__ rowptr, const int* __restrict__ rank,
                          int2* __restrict__ slot) {
    int e = blockIdx.x * blockDim.x + threadIdx.x;
    if (e >= EE) return;
    int s = ei[e], d = ei[EE + e];
    int p = rowptr[d] + rank[e];
    float2 a = ((const float2*)eattr)[e];
    unsigned a0 = f2bf(a.x), a1 = f2bf(a.y);
    slot[p] = make_int2(s, (int)(a0 | (a1 << 16)));
}

// ---------------- layer1 attn scalars: asrc/adst = x . Asd (factored) ---------
// one wave / node; lane owns 2 channels (one dword of x_bf).
__global__ __launch_bounds__(256) void k_attn1(const unsigned short* __restrict__ xb,
                       const float* __restrict__ Asd,
                       float* __restrict__ asrc, float* __restrict__ adst) {
    int node = blockIdx.x * 4 + (threadIdx.x >> 6);
    if (node >= NN) return;
    int lane = threadIdx.x & 63;
    unsigned xw = *(const unsigned*)(xb + (size_t)node * 128 + lane * 2);
    float2 xc = bfpair(xw);
    const float4* A4 = (const float4*)Asd;     // [k][8] -> float4 pairs
    float4 s0 = A4[lane * 4 + 0];              // k=2l  src
    float4 d0 = A4[lane * 4 + 1];              // k=2l  dst
    float4 s1 = A4[lane * 4 + 2];              // k=2l+1 src
    float4 d1 = A4[lane * 4 + 3];              // k=2l+1 dst
    float r[8];
    r[0] = xc.x * s0.x + xc.y * s1.x;
    r[1] = xc.x * s0.y + xc.y * s1.y;
    r[2] = xc.x * s0.z + xc.y * s1.z;
    r[3] = xc.x * s0.w + xc.y * s1.w;
    r[4] = xc.x * d0.x + xc.y * d1.x;
    r[5] = xc.x * d0.y + xc.y * d1.y;
    r[6] = xc.x * d0.z + xc.y * d1.z;
    r[7] = xc.x * d0.w + xc.y * d1.w;
    #pragma unroll
    for (int off = 1; off < 64; off <<= 1)
        #pragma unroll
        for (int j = 0; j < 8; j++) r[j] += __shfl_xor(r[j], off);
    if (lane == 0) {
        *(float4*)(asrc + node * 4) = make_float4(r[0], r[1], r[2], r[3]);
        *(float4*)(adst + node * 4) = make_float4(r[4], r[5], r[6], r[7]);
    }
}

// ---------------- layer1 softmax+aggregate of X (pre-projection) --------------
// one wave / node; quarter-wave (16 lanes x 16B) per edge, 4 edges / iter.
// Packed f32x2 alphas+accumulate (v_pk_fma), exp2-domain (inputs pre-scaled),
// 3-stream rotating clamped prefetch (slot, asrc4, xrow). No main-loop shuffles.
__global__ __launch_bounds__(256) void k_agg1x(const int* __restrict__ rowptr,
                       const int2* __restrict__ slot, const float* __restrict__ asrc,
                       const float* __restrict__ adst, const float* __restrict__ v,
                       const unsigned short* __restrict__ xb,
                       unsigned short* __restrict__ Sx) {
    int node = blockIdx.x * 4 + (threadIdx.x >> 6);
    if (node >= NN) return;
    int lane = threadIdx.x & 63;
    int q  = lane >> 4;          // edge-in-group
    int ql = lane & 15;          // channel-lane: owns ch [ql*8, ql*8+8)
    int beg = rowptr[node], end = rowptr[node + 1];
    float4 pd4 = *(const float4*)(adst + node * 4);
    f32x2 pd01 = {pd4.x, pd4.y}, pd23 = {pd4.z, pd4.w};
    f32x2 v001 = {v[0], v[1]},  v023 = {v[2], v[3]};
    f32x2 v101 = {v[4], v[5]},  v123 = {v[6], v[7]};
    f32x2 acc[4][4] = {};        // [head][chan-pair]
    float den[4] = {};
    float s0 = 0.f, s1 = 0.f;
    const unsigned short* xbq = xb + ql * 8;

    int cnt = end - beg;
    int safeLast = max(end - 1, 0);
    int mend = beg + (cnt & ~3);

    int2 sl0 = slot[min(beg + q, safeLast)];
    int2 sl1 = slot[min(beg + 4 + q, safeLast)];
    float4 as0 = *(const float4*)(asrc + sl0.x * 4);
    uint4  xr0 = *(const uint4*)(xbq + (size_t)sl0.x * 128);

    auto body = [&](int2 cur, float4 cas, uint4 cxr) {
        f32x2 a = bfpair2((unsigned)cur.y);
        f32x2 as01 = {cas.x, cas.y}, as23 = {cas.z, cas.w};
        f32x2 al01 = as01 + pd01 + a.x * v001 + a.y * v101;
        f32x2 al23 = as23 + pd23 + a.x * v023 + a.y * v123;
        float t0 = al01.x, t1 = al01.y, t2 = al23.x, t3 = al23.y;
        t0 = (t0 > 0.f) ? t0 : 0.2f * t0;
        t1 = (t1 > 0.f) ? t1 : 0.2f * t1;
        t2 = (t2 > 0.f) ? t2 : 0.2f * t2;
        t3 = (t3 > 0.f) ? t3 : 0.2f * t3;
        float e0 = __builtin_amdgcn_exp2f(t0);
        float e1 = __builtin_amdgcn_exp2f(t1);
        float e2 = __builtin_amdgcn_exp2f(t2);
        float e3 = __builtin_amdgcn_exp2f(t3);
        den[0] += e0; den[1] += e1; den[2] += e2; den[3] += e3;
        s0 += a.x; s1 += a.y;
        f32x2 xx[4];
        xx[0] = bfpair2(cxr.x); xx[1] = bfpair2(cxr.y);
        xx[2] = bfpair2(cxr.z); xx[3] = bfpair2(cxr.w);
        f32x2 E0 = {e0, e0}, E1 = {e1, e1}, E2 = {e2, e2}, E3 = {e3, e3};
        #pragma unroll
        for (int c = 0; c < 4; c++) {
            acc[0][c] += E0 * xx[c];
            acc[1][c] += E1 * xx[c];
            acc[2][c] += E2 * xx[c];
            acc[3][c] += E3 * xx[c];
        }
    };

    #pragma unroll 2
    for (int pb = beg; pb < mend; pb += 4) {
        int2 cur = sl0; float4 cas = as0; uint4 cxr = xr0;
        sl0 = sl1;
        sl1 = slot[min(pb + 8 + q, safeLast)];
        as0 = *(const float4*)(asrc + sl0.x * 4);
        xr0 = *(const uint4*)(xbq + (size_t)sl0.x * 128);
        body(cur, cas, cxr);
    }
    if (mend + q < end) body(sl0, as0, xr0);   // tail edges

    // cross-quarter reductions
    #pragma unroll
    for (int h = 0; h < 4; h++)
        #pragma unroll
        for (int c = 0; c < 4; c++) {
            acc[h][c].x += __shfl_down(acc[h][c].x, 32);
            acc[h][c].y += __shfl_down(acc[h][c].y, 32);
            acc[h][c].x += __shfl_down(acc[h][c].x, 16);
            acc[h][c].y += __shfl_down(acc[h][c].y, 16);
        }
    #pragma unroll
    for (int h = 0; h < 4; h++) {
        den[h] += __shfl_xor(den[h], 16);
        den[h] += __shfl_xor(den[h], 32);
    }
    s0 += __shfl_xor(s0, 16); s0 += __shfl_xor(s0, 32);
    s1 += __shfl_xor(s1, 16); s1 += __shfl_xor(s1, 32);

    // self-loop: mean attrs over real edges (0 if none)
    float dg = fmaxf((float)cnt, 1.0f);
    float m0a = s0 / dg, m1a = s1 / dg;
    float4 an4 = *(const float4*)(asrc + node * 4);
    float an[4]  = {an4.x, an4.y, an4.z, an4.w};
    float pdv[4] = {pd01.x, pd01.y, pd23.x, pd23.y};
    float w0[4]  = {v001.x, v001.y, v023.x, v023.y};
    float w1[4]  = {v101.x, v101.y, v123.x, v123.y};
    float exs[4];
    #pragma unroll
    for (int h = 0; h < 4; h++) {
        float als = an[h] + pdv[h] + m0a * w0[h] + m1a * w1[h];
        als = (als > 0.f) ? als : 0.2f * als;
        exs[h] = __builtin_amdgcn_exp2f(als);
        den[h] += exs[h];
    }

    if (q == 0) {
        uint4 r = *(const uint4*)(xbq + (size_t)node * 128);
        f32x2 xs[4] = {bfpair2(r.x), bfpair2(r.y), bfpair2(r.z), bfpair2(r.w)};
        #pragma unroll
        for (int h = 0; h < 4; h++) {
            float inv = 1.f / (den[h] + 1e-16f);
            short ov[8];
            #pragma unroll
            for (int c = 0; c < 4; c++) {
                ov[2 * c]     = (short)f2bf((acc[h][c].x + exs[h] * xs[c].x) * inv);
                ov[2 * c + 1] = (short)f2bf((acc[h][c].y + exs[h] * xs[c].y) * inv);
            }
            bf16x8 o8 = {ov[0], ov[1], ov[2], ov[3], ov[4], ov[5], ov[6], ov[7]};
            *(bf16x8*)(Sx + (size_t)node * 512 + h * 128 + ql * 8) = o8;
        }
    }
}

// ---------------- layer1 projection: h2 = ELU(Sx @ W1 (per head) + b1) --------
// grid (4 heads, node/128); per block: 128 rows x 64 cols of head h.
__global__ __launch_bounds__(256) void k_proj1(const unsigned short* __restrict__ Sx,
                       const unsigned short* __restrict__ W1t,
                       const float* __restrict__ b1,
                       unsigned short* __restrict__ h2b) {
    int h = blockIdx.x;
    int wave = threadIdx.x >> 6, lane = threadIdx.x & 63;
    int l16 = lane & 15, quad = lane >> 4;
    int m0 = blockIdx.y * 128 + wave * 32;

    f32x4 acc[2][4];
    #pragma unroll
    for (int mt = 0; mt < 2; mt++)
        #pragma unroll
        for (int nt = 0; nt < 4; nt++)
            acc[mt][nt] = (f32x4){0.f, 0.f, 0.f, 0.f};

    int ar0 = min(m0 + l16, NN - 1);
    int ar1 = min(m0 + 16 + l16, NN - 1);
    const unsigned short* a0 = Sx + (size_t)ar0 * 512 + h * 128 + quad * 8;
    const unsigned short* a1 = Sx + (size_t)ar1 * 512 + h * 128 + quad * 8;
    const unsigned short* bp = W1t + (size_t)(h * 64 + l16) * 128 + quad * 8;

    #pragma unroll
    for (int k0 = 0; k0 < 128; k0 += 32) {
        bf16x8 af0 = *(const bf16x8*)(a0 + k0);
        bf16x8 af1 = *(const bf16x8*)(a1 + k0);
        #pragma unroll
        for (int nt = 0; nt < 4; nt++) {
            bf16x8 bf = *(const bf16x8*)(bp + (size_t)nt * 16 * 128 + k0);
            acc[0][nt] = __builtin_amdgcn_mfma_f32_16x16x32_bf16(af0, bf, acc[0][nt], 0, 0, 0);
            acc[1][nt] = __builtin_amdgcn_mfma_f32_16x16x32_bf16(af1, bf, acc[1][nt], 0, 0, 0);
        }
    }

    float bia[4];
    #pragma unroll
    for (int nt = 0; nt < 4; nt++) bia[nt] = b1[h * 64 + nt * 16 + l16];

    // C layout: col = l16, row = quad*4 + reg
    #pragma unroll
    for (int mt = 0; mt < 2; mt++)
        #pragma unroll
        for (int reg = 0; reg < 4; reg++) {
            int row = m0 + mt * 16 + quad * 4 + reg;
            if (row < NN) {
                #pragma unroll
                for (int nt = 0; nt < 4; nt++) {
                    float va = acc[mt][nt][reg] + bia[nt];
                    va = (va > 0.f) ? va : __expf(va) - 1.f;   // ELU (natural e!)
                    h2b[(size_t)row * 256 + h * 64 + nt * 16 + l16] = f2bf(va);
                }
            }
        }
}

// ---------------- MFMA bf16 GEMM with fused attention-scalar epilogue ---------
// (layer 2 only now) C[M,N] = A[M,K] @ Bt[N,K]^T (bf16 out).
// asrc/adst outputs are scaled by log2e (consumed by exp2-domain k_agg2).
template <int K, int NT, int H>
__global__ __launch_bounds__(256) void gemm_mfma(const unsigned short* __restrict__ A,
                                                 const unsigned short* __restrict__ Bt,
                                                 unsigned short* __restrict__ C,
                                                 const float* __restrict__ avs,
                                                 const float* __restrict__ avd,
                                                 float* __restrict__ asrc,
                                                 float* __restrict__ adst,
                                                 int M, int N) {
    int wave = threadIdx.x >> 6, lane = threadIdx.x & 63;
    int l16 = lane & 15, quad = lane >> 4;
    int m0 = blockIdx.y * 128 + wave * 32;
    int n0 = blockIdx.x * (NT * 16);

    f32x4 acc[2][NT];
    #pragma unroll
    for (int mt = 0; mt < 2; mt++)
        #pragma unroll
        for (int nt = 0; nt < NT; nt++)
            acc[mt][nt] = (f32x4){0.f, 0.f, 0.f, 0.f};

    int ar0 = min(m0 + l16, M - 1);
    int ar1 = min(m0 + 16 + l16, M - 1);
    const unsigned short* a0 = A + (size_t)ar0 * K + quad * 8;
    const unsigned short* a1 = A + (size_t)ar1 * K + quad * 8;
    const unsigned short* bp = Bt + (size_t)(n0 + l16) * K + quad * 8;

    #pragma unroll
    for (int k0 = 0; k0 < K; k0 += 32) {
        bf16x8 af0 = *(const bf16x8*)(a0 + k0);
        bf16x8 af1 = *(const bf16x8*)(a1 + k0);
        #pragma unroll
        for (int nt = 0; nt < NT; nt++) {
            bf16x8 bf = *(const bf16x8*)(bp + (size_t)nt * 16 * K + k0);
            acc[0][nt] = __builtin_amdgcn_mfma_f32_16x16x32_bf16(af0, bf, acc[0][nt], 0, 0, 0);
            acc[1][nt] = __builtin_amdgcn_mfma_f32_16x16x32_bf16(af1, bf, acc[1][nt], 0, 0, 0);
        }
    }

    // C store. C/D layout: col = l16, row = quad*4 + reg
    #pragma unroll
    for (int mt = 0; mt < 2; mt++)
        #pragma unroll
        for (int reg = 0; reg < 4; reg++) {
            int row = m0 + mt * 16 + quad * 4 + reg;
            if (row < M) {
                #pragma unroll
                for (int nt = 0; nt < NT; nt++)
                    C[(size_t)row * N + n0 + nt * 16 + l16] = f2bf(acc[mt][nt][reg]);
            }
        }

    // fused attn scalars: asrc/adst[row, head] from fp32 acc (log2e-scaled)
    float ws[NT], wd[NT];
    #pragma unroll
    for (int nt = 0; nt < NT; nt++) {
        ws[nt] = avs[n0 + nt * 16 + l16] * LOG2E;
        wd[nt] = avd[n0 + nt * 16 + l16] * LOG2E;
    }
    int hh = n0 >> 6;          // head index (layer2: 0)
    #pragma unroll
    for (int mt = 0; mt < 2; mt++)
        #pragma unroll
        for (int reg = 0; reg < 4; reg++) {
            int row = m0 + mt * 16 + quad * 4 + reg;
            float s1 = 0.f, s2 = 0.f;
            #pragma unroll
            for (int nt = 0; nt < NT; nt++) {
                float c = acc[mt][nt][reg];
                s1 += c * ws[nt];
                s2 += c * wd[nt];
            }
            #pragma unroll
            for (int off = 1; off < 16; off <<= 1) {
                s1 += __shfl_xor(s1, off);
                s2 += __shfl_xor(s2, off);
            }
            if (l16 == 0 && row < M) {
                asrc[row * H + hh] = s1;
                adst[row * H + hh] = s2;
            }
        }
}

// ---------------- layer2 fused softmax+aggregate+bias (H=1, 128ch, fp32 out) --
// quarter-wave per edge; packed f32x2 accumulate, exp2-domain alpha, 3-stream
// rotating clamped prefetch (slot, asrc, row).
__global__ __launch_bounds__(256) void k_agg2(const int* __restrict__ rowptr,
                       const int2* __restrict__ slot, const float* __restrict__ asrc,
                       const float* __restrict__ adst, const float* __restrict__ v,
                       const unsigned short* __restrict__ gb, const float* __restrict__ b2,
                       float* __restrict__ outp) {
    int node = blockIdx.x * 4 + (threadIdx.x >> 6);
    if (node >= NN) return;
    int lane = threadIdx.x & 63;
    int q  = lane >> 4;          // edge-in-group
    int ql = lane & 15;          // channel-lane (8 ch each)
    int beg = rowptr[node], end = rowptr[node + 1];
    float ad = adst[node];
    float v0 = v[0], v1 = v[1];
    f32x2 acc[4] = {};
    float den = 0.f, s0 = 0.f, s1 = 0.f;
    const unsigned short* gbq = gb + ql * 8;

    int cnt = end - beg;
    int safeLast = max(end - 1, 0);
    int mend = beg + (cnt & ~3);

    int2 sl0 = slot[min(beg + q, safeLast)];
    int2 sl1 = slot[min(beg + 4 + q, safeLast)];
    float as0 = asrc[sl0.x];
    uint4 xr0 = *(const uint4*)(gbq + (size_t)sl0.x * 128);

    auto body = [&](int2 cur, float cas, uint4 cxr) {
        f32x2 a = bfpair2((unsigned)cur.y);
        float al = cas + ad + a.x * v0 + a.y * v1;
        al = (al > 0.f) ? al : 0.2f * al;
        float e = __builtin_amdgcn_exp2f(al);
        s0 += a.x; s1 += a.y; den += e;
        f32x2 E = {e, e};
        acc[0] += E * bfpair2(cxr.x);
        acc[1] += E * bfpair2(cxr.y);
        acc[2] += E * bfpair2(cxr.z);
        acc[3] += E * bfpair2(cxr.w);
    };

    #pragma unroll 2
    for (int pb = beg; pb < mend; pb += 4) {
        int2 cur = sl0; float cas = as0; uint4 cxr = xr0;
        sl0 = sl1;
        sl1 = slot[min(pb + 8 + q, safeLast)];
        as0 = asrc[sl0.x];
        xr0 = *(const uint4*)(gbq + (size_t)sl0.x * 128);
        body(cur, cas, cxr);
    }
    if (mend + q < end) body(sl0, as0, xr0);   // tail edges

    #pragma unroll
    for (int k = 0; k < 4; k++) {
        acc[k].x += __shfl_down(acc[k].x, 32);
        acc[k].y += __shfl_down(acc[k].y, 32);
        acc[k].x += __shfl_down(acc[k].x, 16);
        acc[k].y += __shfl_down(acc[k].y, 16);
    }
    den += __shfl_xor(den, 16); den += __shfl_xor(den, 32);
    s0  += __shfl_xor(s0, 16);  s0  += __shfl_xor(s0, 32);
    s1  += __shfl_xor(s1, 16);  s1  += __shfl_xor(s1, 32);

    // self-loop epilogue
    float dg = fmaxf((float)cnt, 1.0f);
    float als = asrc[node] + ad + (s0 / dg) * v0 + (s1 / dg) * v1;
    als = (als > 0.f) ? als : 0.2f * als;
    float exs = __builtin_amdgcn_exp2f(als);
    den += exs;

    if (q == 0) {
        uint4 r = *(const uint4*)(gbq + (size_t)node * 128);
        f32x2 xs0 = bfpair2(r.x), xs1 = bfpair2(r.y);
        f32x2 xs2 = bfpair2(r.z), xs3 = bfpair2(r.w);
        float inv = 1.f / (den + 1e-16f);
        float4 o0, o1;
        o0.x = (acc[0].x + exs * xs0.x) * inv + b2[ql * 8 + 0];
        o0.y = (acc[0].y + exs * xs0.y) * inv + b2[ql * 8 + 1];
        o0.z = (acc[1].x + exs * xs1.x) * inv + b2[ql * 8 + 2];
        o0.w = (acc[1].y + exs * xs1.y) * inv + b2[ql * 8 + 3];
        o1.x = (acc[2].x + exs * xs2.x) * inv + b2[ql * 8 + 4];
        o1.y = (acc[2].y + exs * xs2.y) * inv + b2[ql * 8 + 5];
        o1.z = (acc[3].x + exs * xs3.x) * inv + b2[ql * 8 + 6];
        o1.w = (acc[3].y + exs * xs3.y) * inv + b2[ql * 8 + 7];
        *(float4*)(outp + (size_t)node * 128 + ql * 8)     = o0;
        *(float4*)(outp + (size_t)node * 128 + ql * 8 + 4) = o1;
    }
}

extern "C" void kernel_launch(void* const* d_in, const int* in_sizes, int n_in,
                              void* d_out, int out_size, void* d_ws, size_t ws_size,
                              hipStream_t stream) {
    const float* x     = (const float*)d_in[0];
    const int*   ei    = (const int*)d_in[1];      // int32 on device
    const float* eattr = (const float*)d_in[2];
    const float* W1    = (const float*)d_in[3];
    const float* We1   = (const float*)d_in[4];
    const float* as1   = (const float*)d_in[5];
    const float* ad1   = (const float*)d_in[6];
    const float* ae1   = (const float*)d_in[7];
    const float* b1    = (const float*)d_in[8];
    const float* W2    = (const float*)d_in[9];
    const float* We2   = (const float*)d_in[10];
    const float* as2   = (const float*)d_in[11];
    const float* ad2   = (const float*)d_in[12];
    const float* ae2   = (const float*)d_in[13];
    const float* b2    = (const float*)d_in[14];
    float* out = (float*)d_out;

    // ---- workspace carve ----
    int* idg    = (int*)d_ws;                      // NN
    int* rank   = idg + NN;                        // EE
    int* rowptr = rank + EE;                       // NN+16
    int* bsum   = rowptr + NN + 16;                // 32
    int* boff   = bsum + 32;                       // 32
    int2* slot  = (int2*)(boff + 32);              // EE (8B-aligned)
    float* asrc1 = (float*)(slot + EE);            // 4*NN
    float* adst1 = asrc1 + 4 * NN;                 // 4*NN
    float* asrc2 = adst1 + 4 * NN;                 // NN
    float* adst2 = asrc2 + NN;                     // NN
    float* vbuf  = adst2 + NN;                     // 64
    float* Asd   = vbuf + 64;                      // 1024
    unsigned short* ub = (unsigned short*)(((uintptr_t)(Asd + 1024) + 63) & ~(uintptr_t)63);
    unsigned short* x_bf  = ub;                      // NN*128
    unsigned short* W1t   = x_bf + (size_t)NN * 128; // 256*128
    unsigned short* W2t   = W1t + 32768;             // 128*256
    unsigned short* Sx    = W2t + 32768;             // NN*512
    unsigned short* h2_bf = Sx + (size_t)NN * 512;   // NN*256
    unsigned short* g2_bf = Sx;                      // alias: Sx dead after proj1

    hipMemsetAsync(idg, 0, (size_t)NN * sizeof(int), stream);

    // prep (v, Asd, Wt casts, degree hist + rank, x cast) + CSR build
    k_prep<<<9632, 256, 0, stream>>>(We1, ae1, We2, ae2, vbuf, as1, ad1, Asd,
                                     W1, W1t, W2, W2t, ei, idg, rank, x, x_bf);
    k_scan1<<<NB, 512, 0, stream>>>(idg, rowptr, bsum);
    k_scan2<<<1, 64, 0, stream>>>(bsum, boff, rowptr);
    k_scan3<<<NB, 512, 0, stream>>>(rowptr, boff);
    k_scatter<<<(EE + 255) / 256, 256, 0, stream>>>(ei, eattr, rowptr, rank, slot);

    // ---- layer 1 ----  (attn scalars, aggregate x, project)
    k_attn1<<<(NN + 3) / 4, 256, 0, stream>>>(x_bf, Asd, asrc1, adst1);
    k_agg1x<<<(NN + 3) / 4, 256, 0, stream>>>(rowptr, slot, asrc1, adst1, vbuf,
                                              x_bf, Sx);
    k_proj1<<<dim3(4, (NN + 127) / 128), 256, 0, stream>>>(Sx, W1t, b1, h2_bf);

    // ---- layer 2 ----
    gemm_mfma<256, 8, 1><<<dim3(1, (NN + 127) / 128), 256, 0, stream>>>(
        h2_bf, W2t, g2_bf, as2, ad2, asrc2, adst2, NN, 128);
    k_agg2<<<(NN + 3) / 4, 256, 0, stream>>>(rowptr, slot, asrc2, adst2, vbuf + 8,
                                             g2_bf, b2, out);
}